// Round 7
// baseline (443.571 us; speedup 1.0000x reference)
//
#include <hip/hip_runtime.h>
#include <math.h>

#define NPTS 524288
#define HALF (NPTS / 2)
#define TSZ  524288
#define TMASK (TSZ - 1)

typedef __attribute__((ext_vector_type(8))) short v8s;   // 8 x bf16 (4 VGPR)
typedef __attribute__((ext_vector_type(4))) float v4f;   // MFMA C/D frag

#define MFMA16(a, b, c) __builtin_amdgcn_mfma_f32_16x16x32_bf16(a, b, c, 0, 0, 0)

__device__ __constant__ float NLf[16] = {
    16.f, 22.f, 30.f, 42.f, 58.f, 80.f, 110.f, 152.f,
    209.f, 288.f, 397.f, 547.f, 754.f, 1039.f, 1432.f, 1974.f
};

#define CEILX 0xE2
#define CEILY 0xD4
#define CEILZ 0xB8

__device__ __forceinline__ short bf16r(float v) {  // f32 -> bf16 RNE
    unsigned b = __float_as_uint(v);
    b += 0x7FFFu + ((b >> 16) & 1u);
    return (short)(b >> 16);
}
__device__ __forceinline__ unsigned packbf(float a, float b) {
    return (unsigned)(unsigned short)bf16r(a) | ((unsigned)(unsigned short)bf16r(b) << 16);
}

// feature-permutation: B-slot k' <- original feature index (64-wide layers)
// owned (t,q,r) -> k' = 32*(t>>1) + 8q + 4*(t&1) + r
__device__ __forceinline__ int orig64(int kp) {
    return 16 * (2 * (kp >> 5) + ((kp >> 2) & 1)) + 4 * ((kp >> 3) & 3) + (kp & 3);
}

// ---------------- kernel 0: pack fp32 tables -> bf16x2 (4 B/entry) ----------
__global__ __launch_bounds__(256) void pack_tables(
    const float4* __restrict__ tbl, uint2* __restrict__ out)
{
    const int idx = blockIdx.x * 256 + threadIdx.x;   // handles 2 entries
    const float4 t = tbl[idx];
    out[idx] = make_uint2(packbf(t.x, t.y), packbf(t.z, t.w));
}

// ---------------- kernel 1: hash gather (at its divergent-gather L2 floor) --
__global__ __launch_bounds__(256) void ngp_hash2b(
    const float* __restrict__ x, const unsigned* __restrict__ tables_pk,
    unsigned* __restrict__ feats_pk)
{
    const int i = blockIdx.x * 256 + threadIdx.x;    // [0, HALF)
    const int l = blockIdx.y;                        // level (slowest -> L2 locality)
    const float n = NLf[l];
    const unsigned* tbl = tables_pk + (size_t)l * TSZ;

    #pragma unroll
    for (int pp = 0; pp < 2; ++pp) {
        const int p = i + pp * HALF;
        const float xu0 = x[3*p+0] / 3.0f + 0.5f;
        const float xu1 = x[3*p+1] / 3.0f + 0.5f;
        const float xu2 = x[3*p+2] / 3.0f + 0.5f;
        const float p0 = xu0 * n, p1 = xu1 * n, p2 = xu2 * n;
        const float f0 = floorf(p0), f1 = floorf(p1), f2 = floorf(p2);
        const float fr0 = p0 - f0, fr1 = p1 - f1, fr2 = p2 - f2;
        const int vf0 = (int)f0, vf1 = (int)f1, vf2 = (int)f2;
        const int vc0 = (int)ceilf(p0), vc1 = (int)ceilf(p1), vc2 = (int)ceilf(p2);
        float a0 = 0.f, a1 = 0.f;
        #pragma unroll
        for (int k = 0; k < 8; ++k) {
            const unsigned vx = (unsigned)(((CEILX >> k) & 1) ? vc0 : vf0);
            const unsigned vy = (unsigned)(((CEILY >> k) & 1) ? vc1 : vf1);
            const unsigned vz = (unsigned)(((CEILZ >> k) & 1) ? vc2 : vf2);
            const unsigned h = (vx ^ (vy * 2654435761u) ^ (vz * 805459861u)) & TMASK;
            const float wx = (k & 1)        ? fr0 : 1.0f - fr0;
            const float wy = ((k >> 1) & 1) ? fr1 : 1.0f - fr1;
            const float wz = ((k >> 2) & 1) ? fr2 : 1.0f - fr2;
            const float wgt = wx * wy * wz;
            const unsigned tv = tbl[h];
            const float t0 = __uint_as_float(tv << 16);
            const float t1 = __uint_as_float(tv & 0xFFFF0000u);
            a0 = fmaf(wgt, t0, a0);
            a1 = fmaf(wgt, t1, a1);
        }
        feats_pk[(size_t)l * NPTS + p] = packbf(a0, a1);
    }
}

// ---------------- kernel 2: register-resident MFMA MLP ----------------------
// D = W(A)·Z(B): activations stay in registers across all 5 layers; the C/D
// layout of one layer IS the B layout of the next via feature relabeling
// (orig64) folded into weight staging. Only LDS use: weight A-frag reads.
__global__ __launch_bounds__(256) void ngp_mlp_reg(
    const float* __restrict__ x, const float* __restrict__ d,
    const unsigned* __restrict__ feats_pk,
    const float* __restrict__ w1a, const float* __restrict__ b1a,
    const float* __restrict__ w1b, const float* __restrict__ b1b,
    const float* __restrict__ w2a, const float* __restrict__ b2a,
    const float* __restrict__ w2b, const float* __restrict__ b2b,
    const float* __restrict__ w2c, const float* __restrict__ b2c,
    float* __restrict__ out)
{
    __shared__ __align__(16) short sW1a[64 * 40];  // [m=64][k=32] natural
    __shared__ __align__(16) short sW1b[16 * 72];  // [m=16][k'=64] pi-remap
    __shared__ __align__(16) short sW2a[64 * 72];  // [m=64][k'=64] h/posenc/bias map
    __shared__ __align__(16) short sW2b[64 * 72];  // [m=64][k'=64] pi-remap
    __shared__ __align__(16) short sW2c[16 * 72];  // [m=16(3)][k'=64] pi-remap

    const int tid = threadIdx.x;

    // ---- stage weights ----
    for (int idx = tid; idx < 32 * 64; idx += 256) {
        const int k = idx >> 6, m2 = idx & 63;
        sW1a[m2 * 40 + k] = bf16r(w1a[k * 64 + m2]);
    }
    for (int idx = tid; idx < 64 * 16; idx += 256) {
        const int kp = idx >> 4, m2 = idx & 15;
        sW1b[m2 * 72 + kp] = bf16r(w1b[orig64(kp) * 16 + m2]);
    }
    for (int idx = tid; idx < 64 * 64; idx += 256) {
        const int kp = idx >> 6, m2 = idx & 63;
        const int kf = kp >> 5, qq = (kp >> 3) & 3, j = kp & 7;
        float v;
        if (kf == 0) {
            const int zo = (j < 4) ? (4 * qq + j) : (16 + 4 * qq + (j - 4));
            v = w2a[zo * 64 + m2];
        } else {
            const int s2 = qq * 8 + j;
            if (s2 < 11)       v = w2a[(32 + s2) * 64 + m2];
            else if (s2 == 31) v = b2a[m2];          // bias folded at k'=63
            else               v = 0.f;
        }
        sW2a[m2 * 72 + kp] = bf16r(v);
    }
    for (int idx = tid; idx < 64 * 64; idx += 256) {
        const int kp = idx >> 6, m2 = idx & 63;
        sW2b[m2 * 72 + kp] = bf16r(w2b[orig64(kp) * 64 + m2]);
    }
    for (int idx = tid; idx < 64 * 16; idx += 256) {
        const int kp = idx >> 4, m2 = idx & 15;
        sW2c[m2 * 72 + kp] = bf16r(m2 < 3 ? w2c[orig64(kp) * 3 + m2] : 0.f);
    }
    __syncthreads();

    const int wave = tid >> 6, lane = tid & 63;
    const int p = lane & 15, q = lane >> 4;

    // per-lane biases (C-init); L2a bias folded into weights
    float bb1a[4][4], bb2b[4][4], bb1b[4], bb2c[4];
    #pragma unroll
    for (int t = 0; t < 4; ++t)
        #pragma unroll
        for (int r = 0; r < 4; ++r) {
            bb1a[t][r] = b1a[t * 16 + 4 * q + r];
            bb2b[t][r] = b2b[t * 16 + 4 * q + r];
        }
    #pragma unroll
    for (int r = 0; r < 4; ++r) {
        bb1b[r] = b1b[4 * q + r];
        bb2c[r] = (q == 0 && r < 3) ? b2c[r] : 0.f;
    }

    for (int tl = 0; tl < 4; ++tl) {
        const int pbase = blockIdx.x * 256 + wave * 64 + tl * 16;
        const int pt = pbase + p;

        // ---- feats B-frag (natural order: level 4q+j) ----
        union { v8s v; unsigned u[4]; } Bf;
        #pragma unroll
        for (int j = 0; j < 4; ++j)
            Bf.u[j] = feats_pk[(size_t)(4 * q + j) * NPTS + pt];

        // ---- L1a: 4 mtiles, K=32 ----
        v4f a1v[4];
        #pragma unroll
        for (int t = 0; t < 4; ++t) {
            v4f c = {bb1a[t][0], bb1a[t][1], bb1a[t][2], bb1a[t][3]};
            a1v[t] = MFMA16(*(const v8s*)(sW1a + (t * 16 + p) * 40 + q * 8), Bf.v, c);
        }
        // relu + pack -> pi B-frags
        union { v8s v; unsigned u[4]; } B0, B1;
        #pragma unroll
        for (int t = 0; t < 4; ++t) {
            const float r0 = fmaxf(a1v[t][0], 0.f), r1 = fmaxf(a1v[t][1], 0.f);
            const float r2 = fmaxf(a1v[t][2], 0.f), r3 = fmaxf(a1v[t][3], 0.f);
            unsigned* dst = (t < 2) ? B0.u : B1.u;
            dst[(t & 1) * 2 + 0] = packbf(r0, r1);
            dst[(t & 1) * 2 + 1] = packbf(r2, r3);
        }

        // ---- L1b: m=16, 2 kfrags -> h (NO relu) ----
        v4f h = {bb1b[0], bb1b[1], bb1b[2], bb1b[3]};
        h = MFMA16(*(const v8s*)(sW1b + p * 72 + q * 8), B0.v, h);
        h = MFMA16(*(const v8s*)(sW1b + p * 72 + 32 + q * 8), B1.v, h);

        // ---- posenc values ----
        const float dd0 = d[3 * pt + 0], dd1 = d[3 * pt + 1], dd2 = d[3 * pt + 2];
        float zlo[4];   // z[16+4q+u]
        #pragma unroll
        for (int u = 0; u < 4; ++u) {
            const int zo = 16 + 4 * q + u;
            float v;
            if (zo < 19) v = (zo == 16) ? dd0 : ((zo == 17) ? dd1 : dd2);
            else {
                const int idx = zo - 19, e = idx / 6, w = idx % 6;
                const float base = (w % 3 == 0) ? dd0 : ((w % 3 == 1) ? dd1 : dd2);
                const float s = (float)(1 << e) * base;
                v = (w < 3) ? __sinf(s) : __cosf(s);
            }
            zlo[u] = v;
        }
        float zhi[8];   // kfrag1 slot s2=q*8+j
        #pragma unroll
        for (int j = 0; j < 8; ++j) {
            const int s2 = q * 8 + j;
            float v;
            if (s2 < 11) {
                const int zo = 32 + s2;          // 32..42
                const int idx = zo - 19, e = idx / 6, w = idx % 6;
                const float base = (w % 3 == 0) ? dd0 : ((w % 3 == 1) ? dd1 : dd2);
                const float s = (float)(1 << e) * base;
                v = (w < 3) ? __sinf(s) : __cosf(s);
            } else v = (s2 == 31) ? 1.0f : 0.f;  // k'=63 carries folded bias
            zhi[j] = v;
        }

        // ---- L2a B-frags: h at k'=8q..8q+3, posenc rest ----
        union { v8s v; unsigned u[4]; } B2k0, B2k1;
        B2k0.u[0] = packbf(h[0], h[1]);
        B2k0.u[1] = packbf(h[2], h[3]);
        B2k0.u[2] = packbf(zlo[0], zlo[1]);
        B2k0.u[3] = packbf(zlo[2], zlo[3]);
        #pragma unroll
        for (int j = 0; j < 4; ++j) B2k1.u[j] = packbf(zhi[2 * j], zhi[2 * j + 1]);

        // ---- L2a: 4 mtiles x 2 kfrags (bias in k'=63) ----
        v4f a2v[4];
        #pragma unroll
        for (int t = 0; t < 4; ++t) {
            v4f c = {0.f, 0.f, 0.f, 0.f};
            c = MFMA16(*(const v8s*)(sW2a + (t * 16 + p) * 72 + q * 8), B2k0.v, c);
            a2v[t] = MFMA16(*(const v8s*)(sW2a + (t * 16 + p) * 72 + 32 + q * 8), B2k1.v, c);
        }
        union { v8s v; unsigned u[4]; } B3k0, B3k1;
        #pragma unroll
        for (int t = 0; t < 4; ++t) {
            const float r0 = fmaxf(a2v[t][0], 0.f), r1 = fmaxf(a2v[t][1], 0.f);
            const float r2 = fmaxf(a2v[t][2], 0.f), r3 = fmaxf(a2v[t][3], 0.f);
            unsigned* dst = (t < 2) ? B3k0.u : B3k1.u;
            dst[(t & 1) * 2 + 0] = packbf(r0, r1);
            dst[(t & 1) * 2 + 1] = packbf(r2, r3);
        }

        // ---- L2b ----
        v4f a3v[4];
        #pragma unroll
        for (int t = 0; t < 4; ++t) {
            v4f c = {bb2b[t][0], bb2b[t][1], bb2b[t][2], bb2b[t][3]};
            c = MFMA16(*(const v8s*)(sW2b + (t * 16 + p) * 72 + q * 8), B3k0.v, c);
            a3v[t] = MFMA16(*(const v8s*)(sW2b + (t * 16 + p) * 72 + 32 + q * 8), B3k1.v, c);
        }
        union { v8s v; unsigned u[4]; } B4k0, B4k1;
        #pragma unroll
        for (int t = 0; t < 4; ++t) {
            const float r0 = fmaxf(a3v[t][0], 0.f), r1 = fmaxf(a3v[t][1], 0.f);
            const float r2 = fmaxf(a3v[t][2], 0.f), r3 = fmaxf(a3v[t][3], 0.f);
            unsigned* dst = (t < 2) ? B4k0.u : B4k1.u;
            dst[(t & 1) * 2 + 0] = packbf(r0, r1);
            dst[(t & 1) * 2 + 1] = packbf(r2, r3);
        }

        // ---- L2c ----
        v4f cacc = {bb2c[0], bb2c[1], bb2c[2], bb2c[3]};
        cacc = MFMA16(*(const v8s*)(sW2c + p * 72 + q * 8), B4k0.v, cacc);
        cacc = MFMA16(*(const v8s*)(sW2c + p * 72 + 32 + q * 8), B4k1.v, cacc);

        // ---- epilogue (q==0 lanes own rows 0..3 = rgb + h[0]) ----
        if (q == 0) {
            const float xs0 = x[3 * pt + 0] / 3.0f;
            const float xs1 = x[3 * pt + 1] / 3.0f;
            const float xs2 = x[3 * pt + 2] / 3.0f;
            const bool mask = (fabsf(xs0) < 0.5f) & (fabsf(xs1) < 0.5f) & (fabsf(xs2) < 0.5f);
            #pragma unroll
            for (int c = 0; c < 3; ++c) {
                const float cv = 1.0f / (1.0f + __expf(-cacc[c]));
                out[3 * pt + c] = mask ? cv : 0.f;
            }
            out[3 * NPTS + pt] = mask ? __expf(h[0]) : 0.f;
        }
    }
}

// ---------------- fallback: fused VALU kernel (if ws too small) -------------
__global__ __launch_bounds__(256) void ngp_fused(
    const float* __restrict__ x, const float* __restrict__ d,
    const float* __restrict__ tables,
    const float* __restrict__ w1a, const float* __restrict__ b1a,
    const float* __restrict__ w1b, const float* __restrict__ b1b,
    const float* __restrict__ w2a, const float* __restrict__ b2a,
    const float* __restrict__ w2b, const float* __restrict__ b2b,
    const float* __restrict__ w2c, const float* __restrict__ b2c,
    float* __restrict__ out)
{
    const int i = blockIdx.x * 256 + threadIdx.x;
    if (i >= NPTS) return;
    const float xs0 = x[3*i+0] / 3.0f;
    const float xs1 = x[3*i+1] / 3.0f;
    const float xs2 = x[3*i+2] / 3.0f;
    const bool mask = (fabsf(xs0) < 0.5f) & (fabsf(xs1) < 0.5f) & (fabsf(xs2) < 0.5f);
    const float xu0 = xs0 + 0.5f, xu1 = xs1 + 0.5f, xu2 = xs2 + 0.5f;

    float feats[32];
    #pragma unroll
    for (int l = 0; l < 16; ++l) {
        const float n = NLf[l];
        const float p0 = xu0 * n, p1 = xu1 * n, p2 = xu2 * n;
        const float f0 = floorf(p0), f1 = floorf(p1), f2 = floorf(p2);
        const float fr0 = p0 - f0, fr1 = p1 - f1, fr2 = p2 - f2;
        const int vf0 = (int)f0, vf1 = (int)f1, vf2 = (int)f2;
        const int vc0 = (int)ceilf(p0), vc1 = (int)ceilf(p1), vc2 = (int)ceilf(p2);
        const float2* tbl = (const float2*)(tables + (size_t)l * (TSZ * 2));
        float a0 = 0.f, a1 = 0.f;
        #pragma unroll
        for (int k = 0; k < 8; ++k) {
            const unsigned vx = (unsigned)(((CEILX >> k) & 1) ? vc0 : vf0);
            const unsigned vy = (unsigned)(((CEILY >> k) & 1) ? vc1 : vf1);
            const unsigned vz = (unsigned)(((CEILZ >> k) & 1) ? vc2 : vf2);
            const unsigned h = (vx ^ (vy * 2654435761u) ^ (vz * 805459861u)) & TMASK;
            const float wx = (k & 1)        ? fr0 : 1.0f - fr0;
            const float wy = ((k >> 1) & 1) ? fr1 : 1.0f - fr1;
            const float wz = ((k >> 2) & 1) ? fr2 : 1.0f - fr2;
            const float wgt = wx * wy * wz;
            const float2 t = tbl[h];
            a0 = fmaf(wgt, t.x, a0);
            a1 = fmaf(wgt, t.y, a1);
        }
        feats[2*l] = a0; feats[2*l+1] = a1;
    }

    float h2v[16];
    #pragma unroll
    for (int j = 0; j < 16; ++j) h2v[j] = b1b[j];
    #pragma unroll
    for (int c = 0; c < 4; ++c) {
        float h1c[16];
        #pragma unroll
        for (int jj = 0; jj < 16; ++jj) h1c[jj] = b1a[16*c + jj];
        #pragma unroll
        for (int i2 = 0; i2 < 32; ++i2) {
            const float f = feats[i2];
            #pragma unroll
            for (int jj = 0; jj < 16; ++jj)
                h1c[jj] = fmaf(f, w1a[i2*64 + 16*c + jj], h1c[jj]);
        }
        #pragma unroll
        for (int jj = 0; jj < 16; ++jj) {
            const float f = fmaxf(h1c[jj], 0.f);
            #pragma unroll
            for (int t = 0; t < 16; ++t)
                h2v[t] = fmaf(f, w1b[(16*c + jj)*16 + t], h2v[t]);
        }
    }

    float z1[64];
    #pragma unroll
    for (int j = 0; j < 64; ++j) z1[j] = b2a[j];
    #pragma unroll
    for (int i2 = 0; i2 < 16; ++i2) {
        const float f = h2v[i2];
        #pragma unroll
        for (int j = 0; j < 64; ++j) z1[j] = fmaf(f, w2a[i2*64 + j], z1[j]);
    }
    const float d0 = d[3*i+0], d1 = d[3*i+1], d2 = d[3*i+2];
    {
        const float* r = w2a + 16*64;
        #pragma unroll
        for (int j = 0; j < 64; ++j) z1[j] = fmaf(d0, r[j], z1[j]);
        r = w2a + 17*64;
        #pragma unroll
        for (int j = 0; j < 64; ++j) z1[j] = fmaf(d1, r[j], z1[j]);
        r = w2a + 18*64;
        #pragma unroll
        for (int j = 0; j < 64; ++j) z1[j] = fmaf(d2, r[j], z1[j]);
    }
    #pragma unroll
    for (int e = 0; e < 4; ++e) {
        const float mm = (float)(1 << e);
        const float dv[3] = {d0, d1, d2};
        #pragma unroll
        for (int a = 0; a < 3; ++a) {
            const float sv = __sinf(mm * dv[a]);
            const float* rs = w2a + (19 + 6*e + a)*64;
            #pragma unroll
            for (int j = 0; j < 64; ++j) z1[j] = fmaf(sv, rs[j], z1[j]);
        }
        #pragma unroll
        for (int a = 0; a < 3; ++a) {
            const float cv = __cosf(mm * dv[a]);
            const float* rc = w2a + (19 + 6*e + 3 + a)*64;
            #pragma unroll
            for (int j = 0; j < 64; ++j) z1[j] = fmaf(cv, rc[j], z1[j]);
        }
    }
    #pragma unroll
    for (int j = 0; j < 64; ++j) z1[j] = fmaxf(z1[j], 0.f);

    float ca = b2c[0], cb = b2c[1], cc = b2c[2];
    #pragma unroll
    for (int jc = 0; jc < 64; jc += 16) {
        float acc[16];
        #pragma unroll
        for (int jj = 0; jj < 16; ++jj) acc[jj] = b2b[jc + jj];
        #pragma unroll
        for (int i2 = 0; i2 < 64; ++i2) {
            const float f = z1[i2];
            #pragma unroll
            for (int jj = 0; jj < 16; ++jj)
                acc[jj] = fmaf(f, w2b[i2*64 + jc + jj], acc[jj]);
        }
        #pragma unroll
        for (int jj = 0; jj < 16; ++jj) {
            const float v = fmaxf(acc[jj], 0.f);
            ca = fmaf(v, w2c[(jc + jj)*3 + 0], ca);
            cb = fmaf(v, w2c[(jc + jj)*3 + 1], cb);
            cc = fmaf(v, w2c[(jc + jj)*3 + 2], cc);
        }
    }

    float r = 1.0f / (1.0f + __expf(-ca));
    float g = 1.0f / (1.0f + __expf(-cb));
    float b = 1.0f / (1.0f + __expf(-cc));
    float sigma;
    if (mask) { sigma = __expf(h2v[0]); }
    else { r = 0.f; g = 0.f; b = 0.f; sigma = 0.f; }
    out[3*i + 0] = r;
    out[3*i + 1] = g;
    out[3*i + 2] = b;
    out[3*NPTS + i] = sigma;
}

extern "C" void kernel_launch(void* const* d_in, const int* in_sizes, int n_in,
                              void* d_out, int out_size, void* d_ws, size_t ws_size,
                              hipStream_t stream) {
    const float* x      = (const float*)d_in[0];
    const float* d      = (const float*)d_in[1];
    const float* tables = (const float*)d_in[2];
    const float* w1a    = (const float*)d_in[3];
    const float* b1a    = (const float*)d_in[4];
    const float* w1b    = (const float*)d_in[5];
    const float* b1b    = (const float*)d_in[6];
    const float* w2a    = (const float*)d_in[7];
    const float* b2a    = (const float*)d_in[8];
    const float* w2b    = (const float*)d_in[9];
    const float* b2b    = (const float*)d_in[10];
    const float* w2c    = (const float*)d_in[11];
    const float* b2c    = (const float*)d_in[12];
    float* out = (float*)d_out;

    // ws layout: [0, 32 MiB) packed feats [L][N]; [32 MiB, 64 MiB) packed tables
    const size_t need = (size_t)16 * NPTS * 4 * 2;   // 64 MiB
    if (ws_size >= need) {
        unsigned* feats_pk  = (unsigned*)d_ws;
        unsigned* tables_pk = (unsigned*)d_ws + (size_t)16 * NPTS;

        dim3 gp(16 * TSZ / (256 * 2)), bp(256);
        hipLaunchKernelGGL(pack_tables, gp, bp, 0, stream,
                           (const float4*)tables, (uint2*)tables_pk);

        dim3 gh(HALF / 256, 16), bh(256);
        hipLaunchKernelGGL(ngp_hash2b, gh, bh, 0, stream, x, tables_pk, feats_pk);

        dim3 gm(NPTS / 256), bm(256);
        hipLaunchKernelGGL(ngp_mlp_reg, gm, bm, 0, stream,
                           x, d, feats_pk, w1a, b1a, w1b, b1b,
                           w2a, b2a, w2b, b2b, w2c, b2c, out);
    } else {
        dim3 grid(NPTS / 256), block(256);
        hipLaunchKernelGGL(ngp_fused, grid, block, 0, stream,
                           x, d, tables, w1a, b1a, w1b, b1b,
                           w2a, b2a, w2b, b2b, w2c, b2c, out);
    }
}

// Round 8
// 351.946 us; speedup vs baseline: 1.2603x; 1.2603x over previous
//
#include <hip/hip_runtime.h>
#include <math.h>

#define NPTS 524288
#define HALF (NPTS / 2)
#define TSZ  524288
#define TMASK (TSZ - 1)

typedef __attribute__((ext_vector_type(8))) short v8s;   // 8 x bf16 (4 VGPR)
typedef __attribute__((ext_vector_type(4))) float v4f;   // MFMA C/D frag

#define MFMA16(a, b, c) __builtin_amdgcn_mfma_f32_16x16x32_bf16(a, b, c, 0, 0, 0)

__device__ __constant__ float NLf[16] = {
    16.f, 22.f, 30.f, 42.f, 58.f, 80.f, 110.f, 152.f,
    209.f, 288.f, 397.f, 547.f, 754.f, 1039.f, 1432.f, 1974.f
};

#define CEILX 0xE2
#define CEILY 0xD4
#define CEILZ 0xB8

__device__ __forceinline__ short bf16r(float v) {  // f32 -> bf16 RNE
    unsigned b = __float_as_uint(v);
    b += 0x7FFFu + ((b >> 16) & 1u);
    return (short)(b >> 16);
}
__device__ __forceinline__ unsigned packbf(float a, float b) {
    return (unsigned)(unsigned short)bf16r(a) | ((unsigned)(unsigned short)bf16r(b) << 16);
}
__device__ __forceinline__ unsigned sel4(uint4 t, unsigned i) {
    const unsigned ab = (i & 1u) ? t.y : t.x;
    const unsigned cd = (i & 1u) ? t.w : t.z;
    return (i & 2u) ? cd : ab;
}

// ---------------- kernel 0: pack fp32 tables -> bf16x2 (4 B/entry) ----------
__global__ __launch_bounds__(256) void pack_tables(
    const float4* __restrict__ tbl, uint2* __restrict__ out)
{
    const int idx = blockIdx.x * 256 + threadIdx.x;   // handles 2 entries
    const float4 t = tbl[idx];
    out[idx] = make_uint2(packbf(t.x, t.y), packbf(t.z, t.w));
}

// ---------------- kernel 1: hash gather, x-pair-merged loads ----------------
// R7 analysis: bound by per-instruction TA transactions (VALU 12%, HBM 9%).
// The 8 vertices form 4 x-pairs whose hashes differ by vf0^vc0 (=2^t-1);
// 75% of pairs fit one aligned uint4 load (diff<=3). x staged via LDS.
__global__ __launch_bounds__(256) void ngp_hash3(
    const float* __restrict__ x, const unsigned* __restrict__ tables_pk,
    unsigned* __restrict__ feats_pk)
{
    __shared__ float sX[2][768];
    const int tid = threadIdx.x;
    const int l = blockIdx.y;
    const float n = NLf[l];
    const unsigned* tbl = tables_pk + (size_t)l * TSZ;

    for (int r = tid; r < 768; r += 256) {
        sX[0][r] = x[(size_t)blockIdx.x * 768 + r];
        sX[1][r] = x[(size_t)(blockIdx.x * 256 + HALF) * 3 + r];
    }
    __syncthreads();

    #pragma unroll
    for (int pp = 0; pp < 2; ++pp) {
        const int p = blockIdx.x * 256 + tid + pp * HALF;
        const float xu0 = sX[pp][tid * 3 + 0] / 3.0f + 0.5f;
        const float xu1 = sX[pp][tid * 3 + 1] / 3.0f + 0.5f;
        const float xu2 = sX[pp][tid * 3 + 2] / 3.0f + 0.5f;

        const float p0 = xu0 * n, p1 = xu1 * n, p2 = xu2 * n;
        const float f0 = floorf(p0), f1 = floorf(p1), f2 = floorf(p2);
        const float fr0 = p0 - f0, fr1 = p1 - f1, fr2 = p2 - f2;
        const float g0 = 1.f - fr0, g1 = 1.f - fr1, g2 = 1.f - fr2;
        const unsigned uvf0 = (unsigned)(int)f0;
        const unsigned uvc0 = (unsigned)(int)ceilf(p0);
        const unsigned syf = (unsigned)(int)f1 * 2654435761u;
        const unsigned syc = (unsigned)(int)ceilf(p1) * 2654435761u;
        const unsigned szf = (unsigned)(int)f2 * 805459861u;
        const unsigned szc = (unsigned)(int)ceilf(p2) * 805459861u;

        // per-vertex weights (original k-bit order; faithful vertex/weight mismatch)
        const float w0 = g0 * g1 * g2,  w1 = fr0 * g1 * g2;
        const float w2 = g0 * fr1 * g2, w6 = g0 * fr1 * fr2;
        const float w3 = fr0 * fr1 * g2, w5 = fr0 * g1 * fr2;
        const float w4 = g0 * g1 * fr2, w7 = fr0 * fr1 * fr2;

        // 4 x-pairs: (S, w_floor, w_ceil)
        const unsigned Ss[4] = { syf ^ szf, syc ^ szf, syf ^ szc, syc ^ szc };
        const float wf[4] = { w0, w2, w3, w4 };
        const float wc[4] = { w1, w6, w5, w7 };

        float a0 = 0.f, a1 = 0.f;
        #pragma unroll
        for (int pr = 0; pr < 4; ++pr) {
            const unsigned hf = (Ss[pr] ^ uvf0) & TMASK;
            const unsigned hc = (Ss[pr] ^ uvc0) & TMASK;
            const unsigned diff = hf ^ hc;
            const uint4 tv = *(const uint4*)(tbl + (hf & ~3u));
            const unsigned ef = sel4(tv, hf & 3u);
            unsigned ec;
            if (diff <= 3u) ec = sel4(tv, hc & 3u);
            else            ec = tbl[hc];
            a0 = fmaf(wf[pr], __uint_as_float(ef << 16), a0);
            a1 = fmaf(wf[pr], __uint_as_float(ef & 0xFFFF0000u), a1);
            a0 = fmaf(wc[pr], __uint_as_float(ec << 16), a0);
            a1 = fmaf(wc[pr], __uint_as_float(ec & 0xFFFF0000u), a1);
        }
        feats_pk[(size_t)l * NPTS + p] = packbf(a0, a1);
    }
}

// ---------------- kernel 2: MFMA MLP (R6 version — best measured) -----------
#define PZ 72   // z-buffer pitch in shorts (144 B, 16B-aligned)

__global__ __launch_bounds__(512) void ngp_mlp_mfma2(
    const float* __restrict__ x, const float* __restrict__ d,
    const unsigned* __restrict__ feats_pk,
    const float* __restrict__ w1a, const float* __restrict__ b1a,
    const float* __restrict__ w1b, const float* __restrict__ b1b,
    const float* __restrict__ w2a, const float* __restrict__ b2a,
    const float* __restrict__ w2b, const float* __restrict__ b2b,
    const float* __restrict__ w2c, const float* __restrict__ b2c,
    float* __restrict__ out)
{
    __shared__ short sW1a[64 * 40];
    __shared__ short sW1b[16 * 72];
    __shared__ short sW2a[64 * 72];
    __shared__ short sW2b[64 * 72];
    __shared__ short sW2c[16 * 72];
    __shared__ short sZ[8 * 2 * 16 * PZ];
    __shared__ float sMask[8 * 32];

    const int tid = threadIdx.x;

    for (int idx = tid; idx < 32 * 64; idx += 512) {
        const int k = idx >> 6, n2 = idx & 63;
        sW1a[n2 * 40 + k] = bf16r(w1a[k * 64 + n2]);
    }
    for (int idx = tid; idx < 64 * 16; idx += 512) {
        const int k = idx >> 4, n2 = idx & 15;
        sW1b[n2 * 72 + k] = bf16r(w1b[k * 16 + n2]);
    }
    for (int idx = tid; idx < 64 * 64; idx += 512) {
        const int k = idx >> 6, n2 = idx & 63;
        sW2a[n2 * 72 + k] = bf16r(k < 43 ? w2a[k * 64 + n2] : 0.f);
    }
    for (int idx = tid; idx < 64 * 64; idx += 512) {
        const int k = idx >> 6, n2 = idx & 63;
        sW2b[n2 * 72 + k] = bf16r(w2b[k * 64 + n2]);
    }
    for (int idx = tid; idx < 64 * 16; idx += 512) {
        const int k = idx >> 4, n2 = idx & 15;
        sW2c[n2 * 72 + k] = bf16r(n2 < 3 ? w2c[k * 3 + n2] : 0.f);
    }
    __syncthreads();

    const int wave = tid >> 6, lane = tid & 63;
    const int m = lane & 15, q = lane >> 4;
    short* zbs[2] = { &sZ[(wave * 2 + 0) * 16 * PZ], &sZ[(wave * 2 + 1) * 16 * PZ] };

    float bb1a[4], bb2a[4], bb2b[4];
    #pragma unroll
    for (int ct = 0; ct < 4; ++ct) {
        bb1a[ct] = b1a[ct * 16 + m];
        bb2a[ct] = b2a[ct * 16 + m];
        bb2b[ct] = b2b[ct * 16 + m];
    }
    const float bb1b = b1b[m];
    const float bb2c = (m < 3) ? b2c[m] : 0.f;

    const int p0 = (blockIdx.x * 16 + wave * 2) * 16;

    #pragma unroll
    for (int t2 = 0; t2 < 2; ++t2) {
        short* zb = zbs[t2];
        const int pb = p0 + t2 * 16;
        #pragma unroll
        for (int it = 0; it < 4; ++it) {
            const int l = it * 4 + q;
            *(unsigned*)(zb + m * PZ + 2 * l) = feats_pk[(size_t)l * NPTS + pb + m];
        }
    }
    if (lane < 32) {
        const int p = p0 + lane;
        const float xs0 = x[3*p+0] / 3.0f;
        const float xs1 = x[3*p+1] / 3.0f;
        const float xs2 = x[3*p+2] / 3.0f;
        sMask[wave * 32 + lane] =
            ((fabsf(xs0) < 0.5f) && (fabsf(xs1) < 0.5f) && (fabsf(xs2) < 0.5f)) ? 1.f : 0.f;
    }

    #pragma unroll
    for (int t2 = 0; t2 < 2; ++t2) {
        short* zb = zbs[t2];
        const v8s a0 = *(const v8s*)(zb + m * PZ + q * 8);
        #pragma unroll
        for (int ct = 0; ct < 4; ++ct) {
            const float bv = bb1a[ct];
            v4f acc = {bv, bv, bv, bv};
            acc = MFMA16(a0, *(const v8s*)(sW1a + (ct * 16 + m) * 40 + q * 8), acc);
            #pragma unroll
            for (int r = 0; r < 4; ++r)
                zb[(q * 4 + r) * PZ + ct * 16 + m] = bf16r(fmaxf(acc[r], 0.f));
        }
    }

    v4f hacc[2];
    #pragma unroll
    for (int t2 = 0; t2 < 2; ++t2) {
        short* zb = zbs[t2];
        const v8s a10 = *(const v8s*)(zb + m * PZ + q * 8);
        const v8s a11 = *(const v8s*)(zb + m * PZ + 32 + q * 8);
        v4f hv = {bb1b, bb1b, bb1b, bb1b};
        hv = MFMA16(a10, *(const v8s*)(sW1b + m * 72 + q * 8), hv);
        hv = MFMA16(a11, *(const v8s*)(sW1b + m * 72 + 32 + q * 8), hv);
        hacc[t2] = hv;
        #pragma unroll
        for (int r = 0; r < 4; ++r)
            zb[(q * 4 + r) * PZ + m] = bf16r(hv[r]);
    }

    #pragma unroll
    for (int t2 = 0; t2 < 2; ++t2) {
        short* zb = zbs[t2];
        const int p = p0 + t2 * 16 + m;
        const float dd0 = d[3*p+0], dd1 = d[3*p+1], dd2 = d[3*p+2];
        v8s pk;
        #pragma unroll
        for (int j = 0; j < 8; ++j) {
            const int k = 16 + q * 8 + j;
            float v;
            if (k < 19) {
                v = (k == 16) ? dd0 : ((k == 17) ? dd1 : dd2);
            } else if (k < 43) {
                const int idx = k - 19;
                const int e = idx / 6, w = idx - 6 * e;
                const float base = (w == 0 || w == 3) ? dd0 : ((w == 1 || w == 4) ? dd1 : dd2);
                const float s = (float)(1 << e) * base;
                v = (w < 3) ? __sinf(s) : __cosf(s);
            } else {
                v = 0.f;
            }
            pk[j] = bf16r(v);
        }
        *(v8s*)(zb + m * PZ + 16 + q * 8) = pk;
        *(unsigned long long*)(zb + m * PZ + 48 + q * 4) = 0ull;
    }

    #pragma unroll
    for (int t2 = 0; t2 < 2; ++t2) {
        short* zb = zbs[t2];
        const v8s a20 = *(const v8s*)(zb + m * PZ + q * 8);
        const v8s a21 = *(const v8s*)(zb + m * PZ + 32 + q * 8);
        #pragma unroll
        for (int ct = 0; ct < 4; ++ct) {
            const float bv = bb2a[ct];
            v4f acc = {bv, bv, bv, bv};
            acc = MFMA16(a20, *(const v8s*)(sW2a + (ct * 16 + m) * 72 + q * 8), acc);
            acc = MFMA16(a21, *(const v8s*)(sW2a + (ct * 16 + m) * 72 + 32 + q * 8), acc);
            #pragma unroll
            for (int r = 0; r < 4; ++r)
                zb[(q * 4 + r) * PZ + ct * 16 + m] = bf16r(fmaxf(acc[r], 0.f));
        }
    }

    #pragma unroll
    for (int t2 = 0; t2 < 2; ++t2) {
        short* zb = zbs[t2];
        const v8s a20 = *(const v8s*)(zb + m * PZ + q * 8);
        const v8s a21 = *(const v8s*)(zb + m * PZ + 32 + q * 8);
        #pragma unroll
        for (int ct = 0; ct < 4; ++ct) {
            const float bv = bb2b[ct];
            v4f acc = {bv, bv, bv, bv};
            acc = MFMA16(a20, *(const v8s*)(sW2b + (ct * 16 + m) * 72 + q * 8), acc);
            acc = MFMA16(a21, *(const v8s*)(sW2b + (ct * 16 + m) * 72 + 32 + q * 8), acc);
            #pragma unroll
            for (int r = 0; r < 4; ++r)
                zb[(q * 4 + r) * PZ + ct * 16 + m] = bf16r(fmaxf(acc[r], 0.f));
        }
    }

    #pragma unroll
    for (int t2 = 0; t2 < 2; ++t2) {
        short* zb = zbs[t2];
        const int pb = p0 + t2 * 16;
        const v8s a30 = *(const v8s*)(zb + m * PZ + q * 8);
        const v8s a31 = *(const v8s*)(zb + m * PZ + 32 + q * 8);
        v4f cacc = {bb2c, bb2c, bb2c, bb2c};
        cacc = MFMA16(a30, *(const v8s*)(sW2c + m * 72 + q * 8), cacc);
        cacc = MFMA16(a31, *(const v8s*)(sW2c + m * 72 + 32 + q * 8), cacc);

        float mk[4];
        #pragma unroll
        for (int r = 0; r < 4; ++r) mk[r] = sMask[wave * 32 + t2 * 16 + q * 4 + r];

        if (m < 3) {
            #pragma unroll
            for (int r = 0; r < 4; ++r) {
                const float cv = 1.0f / (1.0f + __expf(-cacc[r]));
                out[3 * (pb + q * 4 + r) + m] = (mk[r] > 0.5f) ? cv : 0.f;
            }
        }
        if (m == 0) {
            #pragma unroll
            for (int r = 0; r < 4; ++r)
                out[3 * NPTS + pb + q * 4 + r] = (mk[r] > 0.5f) ? __expf(hacc[t2][r]) : 0.f;
        }
    }
}

// ---------------- fallback: fused VALU kernel (if ws too small) -------------
__global__ __launch_bounds__(256) void ngp_fused(
    const float* __restrict__ x, const float* __restrict__ d,
    const float* __restrict__ tables,
    const float* __restrict__ w1a, const float* __restrict__ b1a,
    const float* __restrict__ w1b, const float* __restrict__ b1b,
    const float* __restrict__ w2a, const float* __restrict__ b2a,
    const float* __restrict__ w2b, const float* __restrict__ b2b,
    const float* __restrict__ w2c, const float* __restrict__ b2c,
    float* __restrict__ out)
{
    const int i = blockIdx.x * 256 + threadIdx.x;
    if (i >= NPTS) return;
    const float xs0 = x[3*i+0] / 3.0f;
    const float xs1 = x[3*i+1] / 3.0f;
    const float xs2 = x[3*i+2] / 3.0f;
    const bool mask = (fabsf(xs0) < 0.5f) & (fabsf(xs1) < 0.5f) & (fabsf(xs2) < 0.5f);
    const float xu0 = xs0 + 0.5f, xu1 = xs1 + 0.5f, xu2 = xs2 + 0.5f;

    float feats[32];
    #pragma unroll
    for (int l = 0; l < 16; ++l) {
        const float n = NLf[l];
        const float p0 = xu0 * n, p1 = xu1 * n, p2 = xu2 * n;
        const float f0 = floorf(p0), f1 = floorf(p1), f2 = floorf(p2);
        const float fr0 = p0 - f0, fr1 = p1 - f1, fr2 = p2 - f2;
        const int vf0 = (int)f0, vf1 = (int)f1, vf2 = (int)f2;
        const int vc0 = (int)ceilf(p0), vc1 = (int)ceilf(p1), vc2 = (int)ceilf(p2);
        const float2* tbl = (const float2*)(tables + (size_t)l * (TSZ * 2));
        float a0 = 0.f, a1 = 0.f;
        #pragma unroll
        for (int k = 0; k < 8; ++k) {
            const unsigned vx = (unsigned)(((CEILX >> k) & 1) ? vc0 : vf0);
            const unsigned vy = (unsigned)(((CEILY >> k) & 1) ? vc1 : vf1);
            const unsigned vz = (unsigned)(((CEILZ >> k) & 1) ? vc2 : vf2);
            const unsigned h = (vx ^ (vy * 2654435761u) ^ (vz * 805459861u)) & TMASK;
            const float wx = (k & 1)        ? fr0 : 1.0f - fr0;
            const float wy = ((k >> 1) & 1) ? fr1 : 1.0f - fr1;
            const float wz = ((k >> 2) & 1) ? fr2 : 1.0f - fr2;
            const float wgt = wx * wy * wz;
            const float2 t = tbl[h];
            a0 = fmaf(wgt, t.x, a0);
            a1 = fmaf(wgt, t.y, a1);
        }
        feats[2*l] = a0; feats[2*l+1] = a1;
    }

    float h2v[16];
    #pragma unroll
    for (int j = 0; j < 16; ++j) h2v[j] = b1b[j];
    #pragma unroll
    for (int c = 0; c < 4; ++c) {
        float h1c[16];
        #pragma unroll
        for (int jj = 0; jj < 16; ++jj) h1c[jj] = b1a[16*c + jj];
        #pragma unroll
        for (int i2 = 0; i2 < 32; ++i2) {
            const float f = feats[i2];
            #pragma unroll
            for (int jj = 0; jj < 16; ++jj)
                h1c[jj] = fmaf(f, w1a[i2*64 + 16*c + jj], h1c[jj]);
        }
        #pragma unroll
        for (int jj = 0; jj < 16; ++jj) {
            const float f = fmaxf(h1c[jj], 0.f);
            #pragma unroll
            for (int t = 0; t < 16; ++t)
                h2v[t] = fmaf(f, w1b[(16*c + jj)*16 + t], h2v[t]);
        }
    }

    float z1[64];
    #pragma unroll
    for (int j = 0; j < 64; ++j) z1[j] = b2a[j];
    #pragma unroll
    for (int i2 = 0; i2 < 16; ++i2) {
        const float f = h2v[i2];
        #pragma unroll
        for (int j = 0; j < 64; ++j) z1[j] = fmaf(f, w2a[i2*64 + j], z1[j]);
    }
    const float d0 = d[3*i+0], d1 = d[3*i+1], d2 = d[3*i+2];
    {
        const float* r = w2a + 16*64;
        #pragma unroll
        for (int j = 0; j < 64; ++j) z1[j] = fmaf(d0, r[j], z1[j]);
        r = w2a + 17*64;
        #pragma unroll
        for (int j = 0; j < 64; ++j) z1[j] = fmaf(d1, r[j], z1[j]);
        r = w2a + 18*64;
        #pragma unroll
        for (int j = 0; j < 64; ++j) z1[j] = fmaf(d2, r[j], z1[j]);
    }
    #pragma unroll
    for (int e = 0; e < 4; ++e) {
        const float mm = (float)(1 << e);
        const float dv[3] = {d0, d1, d2};
        #pragma unroll
        for (int a = 0; a < 3; ++a) {
            const float sv = __sinf(mm * dv[a]);
            const float* rs = w2a + (19 + 6*e + a)*64;
            #pragma unroll
            for (int j = 0; j < 64; ++j) z1[j] = fmaf(sv, rs[j], z1[j]);
        }
        #pragma unroll
        for (int a = 0; a < 3; ++a) {
            const float cv = __cosf(mm * dv[a]);
            const float* rc = w2a + (19 + 6*e + 3 + a)*64;
            #pragma unroll
            for (int j = 0; j < 64; ++j) z1[j] = fmaf(cv, rc[j], z1[j]);
        }
    }
    #pragma unroll
    for (int j = 0; j < 64; ++j) z1[j] = fmaxf(z1[j], 0.f);

    float ca = b2c[0], cb = b2c[1], cc = b2c[2];
    #pragma unroll
    for (int jc = 0; jc < 64; jc += 16) {
        float acc[16];
        #pragma unroll
        for (int jj = 0; jj < 16; ++jj) acc[jj] = b2b[jc + jj];
        #pragma unroll
        for (int i2 = 0; i2 < 64; ++i2) {
            const float f = z1[i2];
            #pragma unroll
            for (int jj = 0; jj < 16; ++jj)
                acc[jj] = fmaf(f, w2b[i2*64 + jc + jj], acc[jj]);
        }
        #pragma unroll
        for (int jj = 0; jj < 16; ++jj) {
            const float v = fmaxf(acc[jj], 0.f);
            ca = fmaf(v, w2c[(jc + jj)*3 + 0], ca);
            cb = fmaf(v, w2c[(jc + jj)*3 + 1], cb);
            cc = fmaf(v, w2c[(jc + jj)*3 + 2], cc);
        }
    }

    float r = 1.0f / (1.0f + __expf(-ca));
    float g = 1.0f / (1.0f + __expf(-cb));
    float b = 1.0f / (1.0f + __expf(-cc));
    float sigma;
    if (mask) { sigma = __expf(h2v[0]); }
    else { r = 0.f; g = 0.f; b = 0.f; sigma = 0.f; }
    out[3*i + 0] = r;
    out[3*i + 1] = g;
    out[3*i + 2] = b;
    out[3*NPTS + i] = sigma;
}

extern "C" void kernel_launch(void* const* d_in, const int* in_sizes, int n_in,
                              void* d_out, int out_size, void* d_ws, size_t ws_size,
                              hipStream_t stream) {
    const float* x      = (const float*)d_in[0];
    const float* d      = (const float*)d_in[1];
    const float* tables = (const float*)d_in[2];
    const float* w1a    = (const float*)d_in[3];
    const float* b1a    = (const float*)d_in[4];
    const float* w1b    = (const float*)d_in[5];
    const float* b1b    = (const float*)d_in[6];
    const float* w2a    = (const float*)d_in[7];
    const float* b2a    = (const float*)d_in[8];
    const float* w2b    = (const float*)d_in[9];
    const float* b2b    = (const float*)d_in[10];
    const float* w2c    = (const float*)d_in[11];
    const float* b2c    = (const float*)d_in[12];
    float* out = (float*)d_out;

    // ws layout: [0, 32 MiB) packed feats [L][N]; [32 MiB, 64 MiB) packed tables
    const size_t need = (size_t)16 * NPTS * 4 * 2;   // 64 MiB
    if (ws_size >= need) {
        unsigned* feats_pk  = (unsigned*)d_ws;
        unsigned* tables_pk = (unsigned*)d_ws + (size_t)16 * NPTS;

        dim3 gp(16 * TSZ / (256 * 2)), bp(256);
        hipLaunchKernelGGL(pack_tables, gp, bp, 0, stream,
                           (const float4*)tables, (uint2*)tables_pk);

        dim3 gh(HALF / 256, 16), bh(256);
        hipLaunchKernelGGL(ngp_hash3, gh, bh, 0, stream, x, tables_pk, feats_pk);

        dim3 gm(2048), bm(512);
        hipLaunchKernelGGL(ngp_mlp_mfma2, gm, bm, 0, stream,
                           x, d, feats_pk, w1a, b1a, w1b, b1b,
                           w2a, b2a, w2b, b2b, w2c, b2c, out);
    } else {
        dim3 grid(NPTS / 256), block(256);
        hipLaunchKernelGGL(ngp_fused, grid, block, 0, stream,
                           x, d, tables, w1a, b1a, w1b, b1b,
                           w2a, b2a, w2b, b2b, w2c, b2c, out);
    }
}